// Round 5
// baseline (228.293 us; speedup 1.0000x reference)
//
#include <hip/hip_runtime.h>
#include <hip/hip_bf16.h>

// TensorProductConv, round 5: bucket-by-row + one wave per row, with BOTH the
// edge id AND its col index preloaded into registers at wave start (converged
// loads + shfl broadcast). This removes the per-body cols[e] -> X dependent
// chain, so all 10 loads per body (Y, 4xX, 5xW) are address-ready immediately.
// Unroll-by-4 per half-wave: 8 edges (~80 vmem) in flight per wave to cover
// the random-640B W stream.
//
// X: (V, 4*C) f32, Y: (E, 4) f32, W: (E, 5*C) f32, rows/cols: (E,) int32.
// Z: (V, 11*C) f32.  C = 32, V = 50000, E = 800000 (avg degree 16).

#define C 32
#define ZCOLS (11 * C)
#define MAXDEG 64          // Poisson(16): P(deg > 64) ~ 1e-18 per row; overflow list backs this up
#define OVF_MAX 65536
#define INV_SQRT3 0.57735026918962576451f
#define INV_SQRT2 0.70710678118654752440f

// ---------------- phase 1: bucket edges by destination row ----------------
__global__ void hist_scatter(const int* __restrict__ rows,
                             int* __restrict__ cnt,
                             int* __restrict__ bucket,
                             int* __restrict__ ovf_cnt,
                             int* __restrict__ ovf_list,
                             int E) {
    int e = blockIdx.x * blockDim.x + threadIdx.x;
    if (e >= E) return;
    int r = rows[e];
    int k = atomicAdd(&cnt[r], 1);
    if (k < MAXDEG) {
        bucket[(size_t)r * MAXDEG + k] = e;
    } else {
        int o = atomicAdd(ovf_cnt, 1);
        if (o < OVF_MAX) ovf_list[o] = e;
    }
}

// ---------------- phase 2: one wave per row, register accumulation ----------------
__global__ void tpconv_rows(const float* __restrict__ X,
                            const float* __restrict__ Y,
                            const float* __restrict__ W,
                            const int* __restrict__ cols,
                            const int* __restrict__ cnt,
                            const int* __restrict__ bucket,
                            float* __restrict__ Z,
                            int V) {
    int wid  = blockIdx.x * (blockDim.x >> 6) + (threadIdx.x >> 6);
    int lane = threadIdx.x & 63;
    if (wid >= V) return;
    const int c = lane & 31;   // channel owned by this lane
    const int h = lane >> 5;   // half-wave: h=0 takes even edges, h=1 odd edges

    int n = cnt[wid];          // wave-uniform
    if (n > MAXDEG) n = MAXDEG;

    // Preload the whole bucket list AND its col indices (converged loads).
    const int* bkt = bucket + (size_t)wid * MAXDEG;
    int ebkt = (lane < n) ? bkt[lane] : 0;
    int cbkt = (lane < n) ? cols[ebkt] : 0;

    float acc[11];
#pragma unroll
    for (int j = 0; j < 11; ++j) acc[j] = 0.0f;

    auto body = [&](int e, int col) {
        const float4 y = *reinterpret_cast<const float4*>(Y + (size_t)e * 4);

        const float* Xe = X + (size_t)col * (4 * C);
        const float xj0 = Xe[c];
        const float a0  = Xe[C + 3 * c + 0];
        const float a1  = Xe[C + 3 * c + 1];
        const float a2  = Xe[C + 3 * c + 2];

        // W row is touched by exactly one wave, once: keep it out of L2.
        const float* We = W + (size_t)e * (5 * C);
        const float w0 = __builtin_nontemporal_load(We + 0 * C + c);
        const float w1 = __builtin_nontemporal_load(We + 1 * C + c);
        const float w2 = __builtin_nontemporal_load(We + 2 * C + c);
        const float w3 = __builtin_nontemporal_load(We + 3 * C + c);
        const float w4 = __builtin_nontemporal_load(We + 4 * C + c);

        acc[0] += w0 * xj0 * y.x;

        const float t01 = w1 * xj0;
        acc[1] += t01 * y.y;
        acc[2] += t01 * y.z;
        acc[3] += t01 * y.w;

        const float t10 = w2 * y.x;
        acc[4] += t10 * a0;
        acc[5] += t10 * a1;
        acc[6] += t10 * a2;

        acc[7] += w3 * (a0 * y.y + a1 * y.z + a2 * y.w) * INV_SQRT3;

        const float s = w4 * INV_SQRT2;
        acc[8]  += s * (a1 * y.w - a2 * y.z);
        acc[9]  += s * (a2 * y.y - a0 * y.w);
        acc[10] += s * (a0 * y.z - a1 * y.y);
    };

    // Wave-uniform trip count; all shfls issue while the wave is CONVERGED.
    // Half-wave h handles indices h, h+2, ...; unroll-by-4 gives indices
    // 8j+h+{0,2,4,6}. Max index = 8*jmax-1 <= 63 for n <= 64.
    const int jmax = (n + 7) >> 3;
    for (int j = 0; j < jmax; ++j) {
        const int i0 = 8 * j + h;
        const int i1 = i0 + 2;
        const int i2 = i0 + 4;
        const int i3 = i0 + 6;
        const int e0 = __shfl(ebkt, i0), c0 = __shfl(cbkt, i0);
        const int e1 = __shfl(ebkt, i1), c1 = __shfl(cbkt, i1);
        const int e2 = __shfl(ebkt, i2), c2 = __shfl(cbkt, i2);
        const int e3 = __shfl(ebkt, i3), c3 = __shfl(cbkt, i3);
        if (i0 < n) body(e0, c0);
        if (i1 < n) body(e1, c1);
        if (i2 < n) body(e2, c2);
        if (i3 < n) body(e3, c3);
    }

    // combine the two half-wave partial sums (converged here)
#pragma unroll
    for (int j = 0; j < 11; ++j) acc[j] += __shfl_xor(acc[j], 32);

    if (h == 0) {
        // Z is write-once: nontemporal stores keep it from displacing L2.
        float* Zr = Z + (size_t)wid * ZCOLS;
        __builtin_nontemporal_store(acc[0],  Zr + c);
        __builtin_nontemporal_store(acc[1],  Zr + C + 3 * c + 0);
        __builtin_nontemporal_store(acc[2],  Zr + C + 3 * c + 1);
        __builtin_nontemporal_store(acc[3],  Zr + C + 3 * c + 2);
        __builtin_nontemporal_store(acc[4],  Zr + 4 * C + 3 * c + 0);
        __builtin_nontemporal_store(acc[5],  Zr + 4 * C + 3 * c + 1);
        __builtin_nontemporal_store(acc[6],  Zr + 4 * C + 3 * c + 2);
        __builtin_nontemporal_store(acc[7],  Zr + 7 * C + c);
        __builtin_nontemporal_store(acc[8],  Zr + 8 * C + 3 * c + 0);
        __builtin_nontemporal_store(acc[9],  Zr + 8 * C + 3 * c + 1);
        __builtin_nontemporal_store(acc[10], Zr + 8 * C + 3 * c + 2);
    }
}

// ---------------- phase 3: rare-overflow fallback (normally 0 edges) ----------------
__global__ void ovf_apply(const float* __restrict__ X,
                          const float* __restrict__ Y,
                          const float* __restrict__ W,
                          const int* __restrict__ rows,
                          const int* __restrict__ cols,
                          const int* __restrict__ ovf_cnt,
                          const int* __restrict__ ovf_list,
                          float* __restrict__ Z) {
    int no = *ovf_cnt;
    if (no > OVF_MAX) no = OVF_MAX;
    int total = no * C;
    for (int t = blockIdx.x * blockDim.x + threadIdx.x; t < total;
         t += gridDim.x * blockDim.x) {
        const int i = t >> 5, c = t & 31;
        const int e = ovf_list[i];
        const float4 y = *reinterpret_cast<const float4*>(Y + (size_t)e * 4);
        const int row = rows[e];
        const int col = cols[e];
        const float* Xe = X + (size_t)col * (4 * C);
        const float xj0 = Xe[c];
        const float a0  = Xe[C + 3 * c + 0];
        const float a1  = Xe[C + 3 * c + 1];
        const float a2  = Xe[C + 3 * c + 2];
        const float* We = W + (size_t)e * (5 * C);
        const float w0 = We[c], w1 = We[C + c], w2 = We[2 * C + c],
                    w3 = We[3 * C + c], w4 = We[4 * C + c];
        float* Zr = Z + (size_t)row * ZCOLS;
        atomicAdd(&Zr[c], w0 * xj0 * y.x);
        const float t01 = w1 * xj0;
        atomicAdd(&Zr[C + 3 * c + 0], t01 * y.y);
        atomicAdd(&Zr[C + 3 * c + 1], t01 * y.z);
        atomicAdd(&Zr[C + 3 * c + 2], t01 * y.w);
        const float t10 = w2 * y.x;
        atomicAdd(&Zr[4 * C + 3 * c + 0], t10 * a0);
        atomicAdd(&Zr[4 * C + 3 * c + 1], t10 * a1);
        atomicAdd(&Zr[4 * C + 3 * c + 2], t10 * a2);
        atomicAdd(&Zr[7 * C + c], w3 * (a0 * y.y + a1 * y.z + a2 * y.w) * INV_SQRT3);
        const float s = w4 * INV_SQRT2;
        atomicAdd(&Zr[8 * C + 3 * c + 0], s * (a1 * y.w - a2 * y.z));
        atomicAdd(&Zr[8 * C + 3 * c + 1], s * (a2 * y.y - a0 * y.w));
        atomicAdd(&Zr[8 * C + 3 * c + 2], s * (a0 * y.z - a1 * y.y));
    }
}

extern "C" void kernel_launch(void* const* d_in, const int* in_sizes, int n_in,
                              void* d_out, int out_size, void* d_ws, size_t ws_size,
                              hipStream_t stream) {
    const float* X    = (const float*)d_in[0];
    const float* Y    = (const float*)d_in[1];
    const float* W    = (const float*)d_in[2];
    const int*   rows = (const int*)d_in[3];
    const int*   cols = (const int*)d_in[4];
    float*       Z    = (float*)d_out;

    const int E = in_sizes[1] / 4;        // Y is (E, 4)
    const int V = in_sizes[0] / (4 * C);  // X is (V, 4*C)

    // workspace layout: [cnt: V][ovf_cnt: 1][ovf_list: OVF_MAX][bucket: V*MAXDEG]
    int* cnt      = (int*)d_ws;
    int* ovf_cnt  = cnt + V;
    int* ovf_list = ovf_cnt + 1;
    int* bucket   = ovf_list + OVF_MAX;

    // zero counters (cnt + ovf_cnt contiguous)
    hipMemsetAsync(cnt, 0, (size_t)(V + 1) * sizeof(int), stream);

    {
        const int threads = 256;
        const int blocks = (E + threads - 1) / threads;
        hist_scatter<<<blocks, threads, 0, stream>>>(rows, cnt, bucket, ovf_cnt,
                                                     ovf_list, E);
    }
    {
        const int threads = 256;                  // 4 waves/block
        const int wavesPerBlock = threads / 64;
        const int blocks = (V + wavesPerBlock - 1) / wavesPerBlock;
        tpconv_rows<<<blocks, threads, 0, stream>>>(X, Y, W, cols, cnt, bucket, Z, V);
    }
    {
        ovf_apply<<<64, 256, 0, stream>>>(X, Y, W, rows, cols, ovf_cnt, ovf_list, Z);
    }
}

// Round 6
// 224.045 us; speedup vs baseline: 1.0190x; 1.0190x over previous
//
#include <hip/hip_runtime.h>
#include <hip/hip_bf16.h>

// TensorProductConv, round 6: persistent-wave row processing.
//  - Phase 1 buckets (edge, col) PAIRS per destination row (int2), so phase 2's
//    prologue is two independent loads (no dependent cols[] gather).
//  - Phase 2: 6144 persistent waves grid-stride over rows (~8 rows each):
//    Poisson-degree imbalance averages within a wave, no 4-wave block
//    retirement quantization. Next-row (cnt, pairs) prefetched before
//    processing the current row.
//  - Plain (cached) W loads restored (R2 A/B: nontemporal was slightly worse —
//    loses inter-replay L3 reuse of the W tail).
//
// X: (V, 4*C) f32, Y: (E, 4) f32, W: (E, 5*C) f32, rows/cols: (E,) int32.
// Z: (V, 11*C) f32.  C = 32, V = 50000, E = 800000 (avg degree 16).

#define C 32
#define ZCOLS (11 * C)
#define MAXDEG 64          // Poisson(16): P(deg > 64) ~ 1e-18 per row; overflow list backs this up
#define OVF_MAX 65536
#define INV_SQRT3 0.57735026918962576451f
#define INV_SQRT2 0.70710678118654752440f

struct alignas(8) EdgeCol { int e; int c; };

// ---------------- phase 1: bucket (edge, col) by destination row ----------------
__global__ void hist_scatter(const int* __restrict__ rows,
                             const int* __restrict__ cols,
                             int* __restrict__ cnt,
                             EdgeCol* __restrict__ bucket,
                             int* __restrict__ ovf_cnt,
                             int* __restrict__ ovf_list,
                             int E) {
    int e = blockIdx.x * blockDim.x + threadIdx.x;
    if (e >= E) return;
    int r = rows[e];
    int k = atomicAdd(&cnt[r], 1);
    if (k < MAXDEG) {
        EdgeCol p;
        p.e = e;
        p.c = cols[e];
        bucket[(size_t)r * MAXDEG + k] = p;
    } else {
        int o = atomicAdd(ovf_cnt, 1);
        if (o < OVF_MAX) ovf_list[o] = e;
    }
}

// ---------------- phase 2: persistent waves, one row at a time ----------------
__global__ void tpconv_rows(const float* __restrict__ X,
                            const float* __restrict__ Y,
                            const float* __restrict__ W,
                            const int* __restrict__ cnt,
                            const EdgeCol* __restrict__ bucket,
                            float* __restrict__ Z,
                            int V) {
    const int nwaves = (gridDim.x * blockDim.x) >> 6;
    const int wave   = (blockIdx.x * blockDim.x + threadIdx.x) >> 6;
    const int lane   = threadIdx.x & 63;
    const int c = lane & 31;   // channel owned by this lane
    const int h = lane >> 5;   // half-wave: h=0 takes even edges, h=1 odd edges

    if (wave >= V) return;

    // prologue for the first row: two INDEPENDENT loads (pairs beyond n hold
    // garbage but are never used as shfl sources with index >= n)
    int n_cur = cnt[wave];
    EdgeCol p_cur = bucket[(size_t)wave * MAXDEG + lane];

    for (int row = wave; row < V; row += nwaves) {
        const int row_nxt = row + nwaves;
        int n_nxt = 0;
        EdgeCol p_nxt;
        p_nxt.e = 0; p_nxt.c = 0;
        if (row_nxt < V) {           // prefetch next row while we crunch this one
            n_nxt = cnt[row_nxt];
            p_nxt = bucket[(size_t)row_nxt * MAXDEG + lane];
        }

        int n = n_cur;
        if (n > MAXDEG) n = MAXDEG;
        int eb = p_cur.e;
        int cb = p_cur.c;

        float acc[11];
#pragma unroll
        for (int j = 0; j < 11; ++j) acc[j] = 0.0f;

        auto body = [&](int e, int col) {
            const float4 y = *reinterpret_cast<const float4*>(Y + (size_t)e * 4);

            const float* Xe = X + (size_t)col * (4 * C);
            const float xj0 = Xe[c];
            const float a0  = Xe[C + 3 * c + 0];
            const float a1  = Xe[C + 3 * c + 1];
            const float a2  = Xe[C + 3 * c + 2];

            const float* We = W + (size_t)e * (5 * C);
            const float w0 = We[0 * C + c];
            const float w1 = We[1 * C + c];
            const float w2 = We[2 * C + c];
            const float w3 = We[3 * C + c];
            const float w4 = We[4 * C + c];

            acc[0] += w0 * xj0 * y.x;

            const float t01 = w1 * xj0;
            acc[1] += t01 * y.y;
            acc[2] += t01 * y.z;
            acc[3] += t01 * y.w;

            const float t10 = w2 * y.x;
            acc[4] += t10 * a0;
            acc[5] += t10 * a1;
            acc[6] += t10 * a2;

            acc[7] += w3 * (a0 * y.y + a1 * y.z + a2 * y.w) * INV_SQRT3;

            const float s = w4 * INV_SQRT2;
            acc[8]  += s * (a1 * y.w - a2 * y.z);
            acc[9]  += s * (a2 * y.y - a0 * y.w);
            acc[10] += s * (a0 * y.z - a1 * y.y);
        };

        // Wave-uniform trip count; shfls issue while the wave is CONVERGED.
        // Half-wave h handles indices h, h+2, ...; unroll-by-2 gives indices
        // 4j+h and 4j+2+h. Max index 4*jmax-1 <= 63 for n <= 64.
        const int jmax = (n + 3) >> 2;
        for (int j = 0; j < jmax; ++j) {
            const int ia = 4 * j + h;
            const int ib = ia + 2;
            const int ea = __shfl(eb, ia), ca = __shfl(cb, ia);
            const int e2 = __shfl(eb, ib), c2 = __shfl(cb, ib);
            if (ia < n) body(ea, ca);
            if (ib < n) body(e2, c2);
        }

        // combine the two half-wave partial sums (converged here)
#pragma unroll
        for (int j = 0; j < 11; ++j) acc[j] += __shfl_xor(acc[j], 32);

        if (h == 0) {
            float* Zr = Z + (size_t)row * ZCOLS;
            Zr[c]                 = acc[0];
            Zr[C + 3 * c + 0]     = acc[1];
            Zr[C + 3 * c + 1]     = acc[2];
            Zr[C + 3 * c + 2]     = acc[3];
            Zr[4 * C + 3 * c + 0] = acc[4];
            Zr[4 * C + 3 * c + 1] = acc[5];
            Zr[4 * C + 3 * c + 2] = acc[6];
            Zr[7 * C + c]         = acc[7];
            Zr[8 * C + 3 * c + 0] = acc[8];
            Zr[8 * C + 3 * c + 1] = acc[9];
            Zr[8 * C + 3 * c + 2] = acc[10];
        }

        n_cur = n_nxt;
        p_cur = p_nxt;
    }
}

// ---------------- phase 3: rare-overflow fallback (normally 0 edges) ----------------
__global__ void ovf_apply(const float* __restrict__ X,
                          const float* __restrict__ Y,
                          const float* __restrict__ W,
                          const int* __restrict__ rows,
                          const int* __restrict__ cols,
                          const int* __restrict__ ovf_cnt,
                          const int* __restrict__ ovf_list,
                          float* __restrict__ Z) {
    int no = *ovf_cnt;
    if (no > OVF_MAX) no = OVF_MAX;
    int total = no * C;
    for (int t = blockIdx.x * blockDim.x + threadIdx.x; t < total;
         t += gridDim.x * blockDim.x) {
        const int i = t >> 5, c = t & 31;
        const int e = ovf_list[i];
        const float4 y = *reinterpret_cast<const float4*>(Y + (size_t)e * 4);
        const int row = rows[e];
        const int col = cols[e];
        const float* Xe = X + (size_t)col * (4 * C);
        const float xj0 = Xe[c];
        const float a0  = Xe[C + 3 * c + 0];
        const float a1  = Xe[C + 3 * c + 1];
        const float a2  = Xe[C + 3 * c + 2];
        const float* We = W + (size_t)e * (5 * C);
        const float w0 = We[c], w1 = We[C + c], w2 = We[2 * C + c],
                    w3 = We[3 * C + c], w4 = We[4 * C + c];
        float* Zr = Z + (size_t)row * ZCOLS;
        atomicAdd(&Zr[c], w0 * xj0 * y.x);
        const float t01 = w1 * xj0;
        atomicAdd(&Zr[C + 3 * c + 0], t01 * y.y);
        atomicAdd(&Zr[C + 3 * c + 1], t01 * y.z);
        atomicAdd(&Zr[C + 3 * c + 2], t01 * y.w);
        const float t10 = w2 * y.x;
        atomicAdd(&Zr[4 * C + 3 * c + 0], t10 * a0);
        atomicAdd(&Zr[4 * C + 3 * c + 1], t10 * a1);
        atomicAdd(&Zr[4 * C + 3 * c + 2], t10 * a2);
        atomicAdd(&Zr[7 * C + c], w3 * (a0 * y.y + a1 * y.z + a2 * y.w) * INV_SQRT3);
        const float s = w4 * INV_SQRT2;
        atomicAdd(&Zr[8 * C + 3 * c + 0], s * (a1 * y.w - a2 * y.z));
        atomicAdd(&Zr[8 * C + 3 * c + 1], s * (a2 * y.y - a0 * y.w));
        atomicAdd(&Zr[8 * C + 3 * c + 2], s * (a0 * y.z - a1 * y.y));
    }
}

extern "C" void kernel_launch(void* const* d_in, const int* in_sizes, int n_in,
                              void* d_out, int out_size, void* d_ws, size_t ws_size,
                              hipStream_t stream) {
    const float* X    = (const float*)d_in[0];
    const float* Y    = (const float*)d_in[1];
    const float* W    = (const float*)d_in[2];
    const int*   rows = (const int*)d_in[3];
    const int*   cols = (const int*)d_in[4];
    float*       Z    = (float*)d_out;

    const int E = in_sizes[1] / 4;        // Y is (E, 4)
    const int V = in_sizes[0] / (4 * C);  // X is (V, 4*C)

    // workspace layout: [bucket: V*MAXDEG EdgeCol (8B, aligned at 0)]
    //                   [cnt: V ints][ovf_cnt: 1][ovf_list: OVF_MAX]
    EdgeCol* bucket   = (EdgeCol*)d_ws;
    int*     cnt      = (int*)(bucket + (size_t)V * MAXDEG);
    int*     ovf_cnt  = cnt + V;
    int*     ovf_list = ovf_cnt + 1;

    // zero counters (cnt + ovf_cnt contiguous)
    hipMemsetAsync(cnt, 0, (size_t)(V + 1) * sizeof(int), stream);

    {
        const int threads = 256;
        const int blocks = (E + threads - 1) / threads;
        hist_scatter<<<blocks, threads, 0, stream>>>(rows, cols, cnt, bucket,
                                                     ovf_cnt, ovf_list, E);
    }
    {
        const int threads = 256;                  // 4 waves/block
        const int blocks = 1536;                  // 6144 persistent waves, ~8 rows each
        tpconv_rows<<<blocks, threads, 0, stream>>>(X, Y, W, cnt, bucket, Z, V);
    }
    {
        ovf_apply<<<64, 256, 0, stream>>>(X, Y, W, rows, cols, ovf_cnt, ovf_list, Z);
    }
}